// Round 5
// baseline (1482.209 us; speedup 1.0000x reference)
//
#include <hip/hip_runtime.h>

// e3jLayer: per-edge equivariant tensor product + segment-sum + linear.
// Round 5: kill the scattered-line write tax (198 MB -> ~50 MB).
//   init:        binCur[b] = b*CAP                       (bins of 128 receivers)
//   build_bins:  per 4096-edge block: LDS histogram ranks + one global cursor
//                atomic per (block,bin); write packed (sender<<7|rLow) into
//                per-bin runs (write locality in 18KB regions).
//   fused_gather: one block per bin; LDS accumulator (stride 67 to decorrelate
//                banks); 16 lanes/edge for coalesced 256B nf rows; rsq dir math;
//                LDS f32 atomics; coalesced (acc/32)@W+b epilogue. No CSR.
// Fallback to exact-CSR path (round 3) if ws too small / nbins > 1024.

#define F_DIM 16
#define BIN_SHIFT 7
#define BIN_NODES (1 << BIN_SHIFT)   // 128
#define CHUNK 4096                   // edges per build block
#define ACC_STRIDE 67                // 64 payload + 3 pad (odd -> bank spread)

__global__ void __launch_bounds__(256) init_kernel(int* __restrict__ binCur,
                                                   int nbins, int cap)
{
    int b = blockIdx.x * blockDim.x + threadIdx.x;
    if (b < nbins) binCur[b] = b * cap;
}

__global__ void __launch_bounds__(256) build_bins_kernel(
    const int* __restrict__ senders, const int* __restrict__ receivers,
    int* __restrict__ binCur, int* __restrict__ bins,
    int nbins, int cap, int E)
{
    __shared__ int hist[1024];
    int t = threadIdx.x;
    for (int i = t; i < nbins; i += 256) hist[i] = 0;
    __syncthreads();

    int base = blockIdx.x * CHUNK;
    unsigned pk[16], br[16];
#pragma unroll
    for (int k = 0; k < 16; ++k) {
        int e = base + k * 256 + t;
        if (e < E) {
            int r = receivers[e];
            int s = senders[e];
            int bb = r >> BIN_SHIFT;
            int rank = atomicAdd(&hist[bb], 1);              // LDS atomic
            pk[k] = ((unsigned)s << BIN_SHIFT) | (unsigned)(r & (BIN_NODES - 1));
            br[k] = ((unsigned)bb << 13) | (unsigned)rank;   // bb<=1023, rank<4096
        } else {
            br[k] = 0xFFFFFFFFu;
        }
    }
    __syncthreads();

    // one global cursor atomic per (block, nonzero bin); stash gbase in hist[]
    for (int i = t; i < nbins; i += 256) {
        int c = hist[i];
        if (c > 0) hist[i] = atomicAdd(&binCur[i], c);
    }
    __syncthreads();

#pragma unroll
    for (int k = 0; k < 16; ++k) {
        if (br[k] == 0xFFFFFFFFu) continue;
        int bb   = (int)(br[k] >> 13);
        int rank = (int)(br[k] & 8191u);
        int dest = hist[bb] + rank;
        if (dest < (bb + 1) * cap)   // overflow clip (prob ~1e-14)
            bins[dest] = (int)pk[k];
    }
}

__global__ void __launch_bounds__(256, 4) fused_gather_kernel(
    const float* __restrict__ pos,
    const float* __restrict__ nf,
    const int* __restrict__ bins,
    const int* __restrict__ binCur,
    const float* __restrict__ W,
    const float* __restrict__ Bias,
    float* __restrict__ out,
    int N, int cap)
{
    __shared__ float acc[BIN_NODES * ACC_STRIDE];  // 34.3 KB
    __shared__ float posr[BIN_NODES * 3];          // 1.5 KB

    const float INV_S3 = 0.5773502691896258f;
    const float INV_S2 = 0.7071067811865476f;

    int t = threadIdx.x;
    int bin = blockIdx.x;
    int node0 = bin << BIN_SHIFT;

    for (int i = t; i < BIN_NODES * ACC_STRIDE; i += 256) acc[i] = 0.f;
    if (t < BIN_NODES) {
        int n = node0 + t;
        float px = 0.f, py = 0.f, pz = 0.f;
        if (n < N) { px = pos[3*n]; py = pos[3*n+1]; pz = pos[3*n+2]; }
        posr[t*3] = px; posr[t*3+1] = py; posr[t*3+2] = pz;
    }
    int cnt = binCur[bin] - bin * cap;
    if (cnt > cap) cnt = cap;
    __syncthreads();

    int f = t & 15;
    int base = bin * cap;
    const float4* nf4 = (const float4*)nf;

    for (int j = (t >> 4); j < cnt; j += 16) {
        unsigned pkd = (unsigned)bins[base + j];   // broadcast across 16 lanes
        int s  = (int)(pkd >> BIN_SHIFT);
        int rl = (int)(pkd & (BIN_NODES - 1));

        float dx = posr[rl*3]   - pos[3*s];
        float dy = posr[rl*3+1] - pos[3*s+1];
        float dz = posr[rl*3+2] - pos[3*s+2];
        float d2 = dx*dx + dy*dy + dz*dz;
        float inv = __builtin_amdgcn_rsqf(fmaxf(d2, 1e-18f));  // self-edge -> d=0
        dx *= inv; dy *= inv; dz *= inv;

        float4 x = nf4[(unsigned)(s * F_DIM + f)];  // coalesced 256B row
        float x0 = x.x, x1 = x.y, x2 = x.z, x3 = x.w;

        float dot = x1*dx + x2*dy + x3*dz;
        float o0 = x0 + dot * INV_S3;
        float c0 = x2*dz - x3*dy;
        float c1 = x3*dx - x1*dz;
        float c2 = x1*dy - x2*dx;
        float o1 = x0*dx + x1 + c0 * INV_S2;
        float o2 = x0*dy + x2 + c1 * INV_S2;
        float o3 = x0*dz + x3 + c2 * INV_S2;

        float* a = &acc[rl * ACC_STRIDE + f * 4];
        atomicAdd(a + 0, o0);
        atomicAdd(a + 1, o1);
        atomicAdd(a + 2, o2);
        atomicAdd(a + 3, o3);
    }
    __syncthreads();

    float w[16];
#pragma unroll
    for (int i = 0; i < 16; ++i) w[i] = W[i];
    float b0 = Bias[0], b1 = Bias[1], b2 = Bias[2], b3 = Bias[3];
    const float sc = 1.0f / 32.0f;

    for (int i = t; i < BIN_NODES * F_DIM; i += 256) {
        int nd = i >> 4, fi = i & 15;
        int n = node0 + nd;
        if (n >= N) continue;
        float* a = &acc[nd * ACC_STRIDE + fi * 4];
        float a0 = a[0]*sc, a1 = a[1]*sc, a2 = a[2]*sc, a3 = a[3]*sc;
        float4 o;
        o.x = a0*w[0] + a1*w[4] + a2*w[8]  + a3*w[12] + b0;
        o.y = a0*w[1] + a1*w[5] + a2*w[9]  + a3*w[13] + b1;
        o.z = a0*w[2] + a1*w[6] + a2*w[10] + a3*w[14] + b2;
        o.w = a0*w[3] + a1*w[7] + a2*w[11] + a3*w[15] + b3;
        ((float4*)out)[(size_t)n * F_DIM + fi] = o;  // coalesced
    }
}

// ---------------- fallback: exact CSR path (round 3) ----------------
__global__ void __launch_bounds__(256) hist_kernel(
    const int* __restrict__ receivers, int* __restrict__ deg,
    int* __restrict__ rank, int E)
{
    int e = blockIdx.x * blockDim.x + threadIdx.x;
    if (e >= E) return;
    rank[e] = atomicAdd(&deg[receivers[e]], 1);
}

__global__ void __launch_bounds__(256) alloc_kernel(
    const int* __restrict__ deg, int* __restrict__ start,
    int* __restrict__ cursor, int N)
{
    __shared__ int tmp[256];
    __shared__ int base;
    int t = threadIdx.x;
    int n = blockIdx.x * blockDim.x + t;
    int v = (n < N) ? deg[n] : 0;
    tmp[t] = v;
    __syncthreads();
    for (int off = 1; off < 256; off <<= 1) {
        int x = (t >= off) ? tmp[t - off] : 0;
        __syncthreads();
        tmp[t] += x;
        __syncthreads();
    }
    int incl = tmp[t];
    if (t == 255) base = atomicAdd(cursor, incl);
    __syncthreads();
    if (n < N) start[n] = base + incl - v;
}

__global__ void __launch_bounds__(256) scatter_kernel(
    const int* __restrict__ senders, const int* __restrict__ receivers,
    const int* __restrict__ rank, const int* __restrict__ start,
    int* __restrict__ csr_s, int E)
{
    int e = blockIdx.x * blockDim.x + threadIdx.x;
    if (e >= E) return;
    csr_s[start[receivers[e]] + rank[e]] = senders[e];
}

__global__ void __launch_bounds__(256) gather_kernel(
    const float* __restrict__ pos,
    const float* __restrict__ nf,
    const int* __restrict__ csr_s,
    const int* __restrict__ start,
    const int* __restrict__ deg,
    const float* __restrict__ W,
    const float* __restrict__ b,
    float* __restrict__ out,
    int N)
{
    const float INV_S3 = 0.5773502691896258f;
    const float INV_S2 = 0.7071067811865476f;

    int tid = blockIdx.x * blockDim.x + threadIdx.x;
    int n = tid >> 4;
    if (n >= N) return;
    int f = tid & 15;

    float rx = pos[3*n], ry = pos[3*n+1], rz = pos[3*n+2];
    int s0 = start[n];
    int dcnt = deg[n];
    float a0 = 0.f, a1 = 0.f, a2 = 0.f, a3 = 0.f;
    const float4* nf4 = (const float4*)nf;

    int s = (dcnt > 0) ? csr_s[s0] : 0;
    for (int j = 0; j < dcnt; ++j) {
        int s_next = (j + 1 < dcnt) ? csr_s[s0 + j + 1] : 0;
        float dx = rx - pos[3*s], dy = ry - pos[3*s+1], dz = rz - pos[3*s+2];
        float d2 = dx*dx + dy*dy + dz*dz;
        float inv = __builtin_amdgcn_rsqf(fmaxf(d2, 1e-18f));
        dx *= inv; dy *= inv; dz *= inv;
        float4 x = nf4[(unsigned)(s * F_DIM + f)];
        float x0 = x.x, x1 = x.y, x2 = x.z, x3 = x.w;
        float dot = x1*dx + x2*dy + x3*dz;
        a0 += x0 + dot * INV_S3;
        float c0 = x2*dz - x3*dy, c1 = x3*dx - x1*dz, c2 = x1*dy - x2*dx;
        a1 += x0*dx + x1 + c0 * INV_S2;
        a2 += x0*dy + x2 + c1 * INV_S2;
        a3 += x0*dz + x3 + c2 * INV_S2;
        s = s_next;
    }
    const float sc = 1.0f / 32.0f;
    a0 *= sc; a1 *= sc; a2 *= sc; a3 *= sc;
    float4 o;
    o.x = a0*W[0] + a1*W[4] + a2*W[8]  + a3*W[12] + b[0];
    o.y = a0*W[1] + a1*W[5] + a2*W[9]  + a3*W[13] + b[1];
    o.z = a0*W[2] + a1*W[6] + a2*W[10] + a3*W[14] + b[2];
    o.w = a0*W[3] + a1*W[7] + a2*W[11] + a3*W[15] + b[3];
    ((float4*)out)[tid] = o;
}

extern "C" void kernel_launch(void* const* d_in, const int* in_sizes, int n_in,
                              void* d_out, int out_size, void* d_ws, size_t ws_size,
                              hipStream_t stream)
{
    const float* pos       = (const float*)d_in[0];
    const float* nf        = (const float*)d_in[1];
    const float* W         = (const float*)d_in[2];
    const float* b         = (const float*)d_in[3];
    const int*   senders   = (const int*)d_in[4];
    const int*   receivers = (const int*)d_in[5];

    int N = in_sizes[0] / 3;
    int E = in_sizes[4];
    float* out = (float*)d_out;
    const int blk = 256;

    int nbins = (N + BIN_NODES - 1) / BIN_NODES;
    int cap   = (E + nbins - 1) / nbins + 512;   // mean + ~8 sigma
    size_t need = ((size_t)nbins * cap + nbins) * sizeof(int);

    if (nbins <= 1024 && ws_size >= need) {
        // ws layout: [binCur(nbins)][bins(nbins*cap)]
        int* binCur = (int*)d_ws;
        int* bins   = binCur + nbins;

        init_kernel<<<(nbins + blk - 1) / blk, blk, 0, stream>>>(binCur, nbins, cap);
        build_bins_kernel<<<(E + CHUNK - 1) / CHUNK, blk, 0, stream>>>(
            senders, receivers, binCur, bins, nbins, cap, E);
        fused_gather_kernel<<<nbins, blk, 0, stream>>>(
            pos, nf, bins, binCur, W, b, out, N, cap);
    } else {
        // ws layout: [cursor(1)][deg(N)][start(N)][rank(E)][csr_s(E)]
        int* cursor = (int*)d_ws;
        int* deg    = cursor + 1;
        int* start  = deg + N;
        int* rank   = start + N;
        int* csr_s  = rank + E;

        hipMemsetAsync(cursor, 0, (size_t)(1 + N) * sizeof(int), stream);
        hist_kernel<<<(E + blk - 1) / blk, blk, 0, stream>>>(receivers, deg, rank, E);
        alloc_kernel<<<(N + blk - 1) / blk, blk, 0, stream>>>(deg, start, cursor, N);
        scatter_kernel<<<(E + blk - 1) / blk, blk, 0, stream>>>(
            senders, receivers, rank, start, csr_s, E);
        long total = (long)N * F_DIM;
        gather_kernel<<<(unsigned)((total + blk - 1) / blk), blk, 0, stream>>>(
            pos, nf, csr_s, start, deg, W, b, out, N);
    }
}

// Round 6
// 304.687 us; speedup vs baseline: 4.8647x; 4.8647x over previous
//
#include <hip/hip_runtime.h>

// e3jLayer: per-edge equivariant tensor product + segment-sum + linear.
// Round 6: binned build (validated ~100us, write locality) + local-CSR-in-LDS
// register gather (round-3's 178us gather shape, minus the 198MB global CSR
// scatter tax).
//   init:       binCur[b] = b*cap                 (bins of 64 receiver nodes)
//   build_bins: per-4096-edge block LDS-histogram ranks, 1 global cursor atomic
//               per (block,bin), packed (sender<<6|rLow) written into per-bin runs
//   bin_gather: block per bin: LDS hist(1 int atomic/edge) -> 64-wide scan ->
//               LDS scatter(1 int atomic/edge) = local CSR; then thread (node,f)
//               register-accumulates its ~32 edges (senders broadcast from LDS),
//               writes (acc/32)@W + b once. Zero f32 atomics anywhere.
// Fallback: exact 3-kernel CSR path (round 3) if sizing constraints fail.

#define F_DIM 16
#define BIN_SHIFT 6
#define BIN_NODES (1 << BIN_SHIFT)   // 64 receivers per bin
#define CHUNK 4096                   // edges per build block
#define CAP_LDS 2816                 // max edges per bin in gather LDS (11.3 KB)

__global__ void __launch_bounds__(256) init_kernel(int* __restrict__ binCur,
                                                   int nbins, int cap)
{
    int b = blockIdx.x * blockDim.x + threadIdx.x;
    if (b < nbins) binCur[b] = b * cap;
}

__global__ void __launch_bounds__(256) build_bins_kernel(
    const int* __restrict__ senders, const int* __restrict__ receivers,
    int* __restrict__ binCur, int* __restrict__ bins,
    int nbins, int cap, int E)
{
    __shared__ int hist[2048];
    int t = threadIdx.x;
    for (int i = t; i < nbins; i += 256) hist[i] = 0;
    __syncthreads();

    int base = blockIdx.x * CHUNK;
    unsigned pk[16], br[16];
#pragma unroll
    for (int k = 0; k < 16; ++k) {
        int e = base + k * 256 + t;
        if (e < E) {
            int r = receivers[e];
            int s = senders[e];
            int bb = r >> BIN_SHIFT;
            int rank = atomicAdd(&hist[bb], 1);              // LDS atomic
            pk[k] = ((unsigned)s << BIN_SHIFT) | (unsigned)(r & (BIN_NODES - 1));
            br[k] = ((unsigned)bb << 13) | (unsigned)rank;   // bb<2048, rank<4096
        } else {
            br[k] = 0xFFFFFFFFu;                             // bb<2048 -> br<16.8M, safe
        }
    }
    __syncthreads();

    // one global cursor atomic per (block, nonzero bin); stash gbase in hist[]
    for (int i = t; i < nbins; i += 256) {
        int c = hist[i];
        if (c > 0) hist[i] = atomicAdd(&binCur[i], c);
    }
    __syncthreads();

#pragma unroll
    for (int k = 0; k < 16; ++k) {
        if (br[k] == 0xFFFFFFFFu) continue;
        int bb   = (int)(br[k] >> 13);
        int rank = (int)(br[k] & 8191u);
        int dest = hist[bb] + rank;
        if (dest < (bb + 1) * cap)   // overflow clip (prob ~1e-13)
            bins[dest] = (int)pk[k];
    }
}

__global__ void __launch_bounds__(256) bin_gather_kernel(
    const float* __restrict__ pos,
    const float* __restrict__ nf,
    const int* __restrict__ bins,
    const int* __restrict__ binCur,
    const float* __restrict__ W,
    const float* __restrict__ Bias,
    float* __restrict__ out,
    int N, int cap)
{
    __shared__ int lcsr[CAP_LDS];          // senders, grouped by local node
    __shared__ int lhist[BIN_NODES];       // hist, then scatter cursor
    __shared__ int lscan[BIN_NODES];       // inclusive scan (end offsets)
    __shared__ int lstart[BIN_NODES];      // exclusive scan (start offsets)

    const float INV_S3 = 0.5773502691896258f;
    const float INV_S2 = 0.7071067811865476f;

    int t = threadIdx.x;
    int bin = blockIdx.x;
    int node0 = bin << BIN_SHIFT;
    int gbase = bin * cap;

    int cnt = binCur[bin] - gbase;
    if (cnt > cap) cnt = cap;

    if (t < BIN_NODES) lhist[t] = 0;
    __syncthreads();

    // pass 1: histogram local receivers (1 int LDS atomic per edge)
    for (int j = t; j < cnt; j += 256)
        atomicAdd(&lhist[((unsigned)bins[gbase + j]) & (BIN_NODES - 1)], 1);
    __syncthreads();

    // 64-wide Hillis-Steele scan
    if (t < BIN_NODES) lscan[t] = lhist[t];
    __syncthreads();
    for (int off = 1; off < BIN_NODES; off <<= 1) {
        int v = (t < BIN_NODES && t >= off) ? lscan[t - off] : 0;
        __syncthreads();
        if (t < BIN_NODES) lscan[t] += v;
        __syncthreads();
    }
    if (t < BIN_NODES) { lstart[t] = lscan[t] - lhist[t]; lhist[t] = 0; }
    __syncthreads();

    // pass 2: scatter senders into local CSR (1 int LDS atomic per edge)
    for (int j = t; j < cnt; j += 256) {
        unsigned pk = (unsigned)bins[gbase + j];
        int rl = (int)(pk & (BIN_NODES - 1));
        int rank = atomicAdd(&lhist[rl], 1);
        lcsr[lstart[rl] + rank] = (int)(pk >> BIN_SHIFT);
    }
    __syncthreads();

    // register gather: thread (node, f), 4 nodes per thread
    float w[16];
#pragma unroll
    for (int i = 0; i < 16; ++i) w[i] = W[i];
    float b0 = Bias[0], b1 = Bias[1], b2 = Bias[2], b3 = Bias[3];
    const float sc = 1.0f / 32.0f;

    int f = t & 15;
    const float4* nf4 = (const float4*)nf;

    for (int nl = t >> 4; nl < BIN_NODES; nl += 16) {
        int n = node0 + nl;
        if (n >= N) break;
        float rx = pos[3*n], ry = pos[3*n+1], rz = pos[3*n+2];
        int s0 = lstart[nl];
        int dcnt = lscan[nl] - s0;

        float a0 = 0.f, a1 = 0.f, a2 = 0.f, a3 = 0.f;
        for (int j = 0; j < dcnt; ++j) {
            int s = lcsr[s0 + j];                       // LDS broadcast to 16 lanes
            float dx = rx - pos[3*s];
            float dy = ry - pos[3*s+1];
            float dz = rz - pos[3*s+2];
            float d2 = dx*dx + dy*dy + dz*dz;
            float inv = __builtin_amdgcn_rsqf(fmaxf(d2, 1e-18f));  // self-edge -> 0
            dx *= inv; dy *= inv; dz *= inv;

            float4 x = nf4[(unsigned)(s * F_DIM + f)];  // coalesced 256B row
            float x0 = x.x, x1 = x.y, x2 = x.z, x3 = x.w;

            float dot = x1*dx + x2*dy + x3*dz;
            a0 += x0 + dot * INV_S3;
            float c0 = x2*dz - x3*dy;
            float c1 = x3*dx - x1*dz;
            float c2 = x1*dy - x2*dx;
            a1 += x0*dx + x1 + c0 * INV_S2;
            a2 += x0*dy + x2 + c1 * INV_S2;
            a3 += x0*dz + x3 + c2 * INV_S2;
        }

        a0 *= sc; a1 *= sc; a2 *= sc; a3 *= sc;
        float4 o;
        o.x = a0*w[0] + a1*w[4] + a2*w[8]  + a3*w[12] + b0;
        o.y = a0*w[1] + a1*w[5] + a2*w[9]  + a3*w[13] + b1;
        o.z = a0*w[2] + a1*w[6] + a2*w[10] + a3*w[14] + b2;
        o.w = a0*w[3] + a1*w[7] + a2*w[11] + a3*w[15] + b3;
        ((float4*)out)[(size_t)n * F_DIM + f] = o;      // coalesced
    }
}

// ---------------- fallback: exact CSR path (round 3) ----------------
__global__ void __launch_bounds__(256) hist_kernel(
    const int* __restrict__ receivers, int* __restrict__ deg,
    int* __restrict__ rank, int E)
{
    int e = blockIdx.x * blockDim.x + threadIdx.x;
    if (e >= E) return;
    rank[e] = atomicAdd(&deg[receivers[e]], 1);
}

__global__ void __launch_bounds__(256) alloc_kernel(
    const int* __restrict__ deg, int* __restrict__ start,
    int* __restrict__ cursor, int N)
{
    __shared__ int tmp[256];
    __shared__ int base;
    int t = threadIdx.x;
    int n = blockIdx.x * blockDim.x + t;
    int v = (n < N) ? deg[n] : 0;
    tmp[t] = v;
    __syncthreads();
    for (int off = 1; off < 256; off <<= 1) {
        int x = (t >= off) ? tmp[t - off] : 0;
        __syncthreads();
        tmp[t] += x;
        __syncthreads();
    }
    int incl = tmp[t];
    if (t == 255) base = atomicAdd(cursor, incl);
    __syncthreads();
    if (n < N) start[n] = base + incl - v;
}

__global__ void __launch_bounds__(256) scatter_kernel(
    const int* __restrict__ senders, const int* __restrict__ receivers,
    const int* __restrict__ rank, const int* __restrict__ start,
    int* __restrict__ csr_s, int E)
{
    int e = blockIdx.x * blockDim.x + threadIdx.x;
    if (e >= E) return;
    csr_s[start[receivers[e]] + rank[e]] = senders[e];
}

__global__ void __launch_bounds__(256) gather_kernel(
    const float* __restrict__ pos,
    const float* __restrict__ nf,
    const int* __restrict__ csr_s,
    const int* __restrict__ start,
    const int* __restrict__ deg,
    const float* __restrict__ W,
    const float* __restrict__ b,
    float* __restrict__ out,
    int N)
{
    const float INV_S3 = 0.5773502691896258f;
    const float INV_S2 = 0.7071067811865476f;

    int tid = blockIdx.x * blockDim.x + threadIdx.x;
    int n = tid >> 4;
    if (n >= N) return;
    int f = tid & 15;

    float rx = pos[3*n], ry = pos[3*n+1], rz = pos[3*n+2];
    int s0 = start[n];
    int dcnt = deg[n];
    float a0 = 0.f, a1 = 0.f, a2 = 0.f, a3 = 0.f;
    const float4* nf4 = (const float4*)nf;

    int s = (dcnt > 0) ? csr_s[s0] : 0;
    for (int j = 0; j < dcnt; ++j) {
        int s_next = (j + 1 < dcnt) ? csr_s[s0 + j + 1] : 0;
        float dx = rx - pos[3*s], dy = ry - pos[3*s+1], dz = rz - pos[3*s+2];
        float d2 = dx*dx + dy*dy + dz*dz;
        float inv = __builtin_amdgcn_rsqf(fmaxf(d2, 1e-18f));
        dx *= inv; dy *= inv; dz *= inv;
        float4 x = nf4[(unsigned)(s * F_DIM + f)];
        float x0 = x.x, x1 = x.y, x2 = x.z, x3 = x.w;
        float dot = x1*dx + x2*dy + x3*dz;
        a0 += x0 + dot * INV_S3;
        float c0 = x2*dz - x3*dy, c1 = x3*dx - x1*dz, c2 = x1*dy - x2*dx;
        a1 += x0*dx + x1 + c0 * INV_S2;
        a2 += x0*dy + x2 + c1 * INV_S2;
        a3 += x0*dz + x3 + c2 * INV_S2;
        s = s_next;
    }
    const float sc = 1.0f / 32.0f;
    a0 *= sc; a1 *= sc; a2 *= sc; a3 *= sc;
    float4 o;
    o.x = a0*W[0] + a1*W[4] + a2*W[8]  + a3*W[12] + b[0];
    o.y = a0*W[1] + a1*W[5] + a2*W[9]  + a3*W[13] + b[1];
    o.z = a0*W[2] + a1*W[6] + a2*W[10] + a3*W[14] + b[2];
    o.w = a0*W[3] + a1*W[7] + a2*W[11] + a3*W[15] + b[3];
    ((float4*)out)[tid] = o;
}

extern "C" void kernel_launch(void* const* d_in, const int* in_sizes, int n_in,
                              void* d_out, int out_size, void* d_ws, size_t ws_size,
                              hipStream_t stream)
{
    const float* pos       = (const float*)d_in[0];
    const float* nf        = (const float*)d_in[1];
    const float* W         = (const float*)d_in[2];
    const float* b         = (const float*)d_in[3];
    const int*   senders   = (const int*)d_in[4];
    const int*   receivers = (const int*)d_in[5];

    int N = in_sizes[0] / 3;
    int E = in_sizes[4];
    float* out = (float*)d_out;
    const int blk = 256;

    int nbins = (N + BIN_NODES - 1) >> BIN_SHIFT;
    int cap   = E / nbins + 453;   // mean + ~10 sigma (Poisson)
    size_t need = ((size_t)nbins * cap + nbins) * sizeof(int);

    if (nbins <= 2048 && cap <= CAP_LDS && ws_size >= need) {
        // ws layout: [binCur(nbins)][bins(nbins*cap)]
        int* binCur = (int*)d_ws;
        int* bins   = binCur + nbins;

        init_kernel<<<(nbins + blk - 1) / blk, blk, 0, stream>>>(binCur, nbins, cap);
        build_bins_kernel<<<(E + CHUNK - 1) / CHUNK, blk, 0, stream>>>(
            senders, receivers, binCur, bins, nbins, cap, E);
        bin_gather_kernel<<<nbins, blk, 0, stream>>>(
            pos, nf, bins, binCur, W, b, out, N, cap);
    } else {
        // ws layout: [cursor(1)][deg(N)][start(N)][rank(E)][csr_s(E)]
        int* cursor = (int*)d_ws;
        int* deg    = cursor + 1;
        int* start  = deg + N;
        int* rank   = start + N;
        int* csr_s  = rank + E;

        hipMemsetAsync(cursor, 0, (size_t)(1 + N) * sizeof(int), stream);
        hist_kernel<<<(E + blk - 1) / blk, blk, 0, stream>>>(receivers, deg, rank, E);
        alloc_kernel<<<(N + blk - 1) / blk, blk, 0, stream>>>(deg, start, cursor, N);
        scatter_kernel<<<(E + blk - 1) / blk, blk, 0, stream>>>(
            senders, receivers, rank, start, csr_s, E);
        long total = (long)N * F_DIM;
        gather_kernel<<<(unsigned)((total + blk - 1) / blk), blk, 0, stream>>>(
            pos, nf, csr_s, start, deg, W, b, out, N);
    }
}

// Round 8
// 279.068 us; speedup vs baseline: 5.3113x; 1.0918x over previous
//
#include <hip/hip_runtime.h>

// e3jLayer: per-edge equivariant tensor product + segment-sum + linear.
// Round 8 (= round 7 with the macro-parameter-capture compile bug fixed: the
// EDGE_ACC macro's param `x` rewrote the member access `pr.x` -> inline fn now).
//   - posf4: positions packed to float4 (1 load instead of 3 per edge endpoint)
//   - bin_gather: inner edge loop unrolled x4 -> 8 outstanding global loads per
//     wave-group (posf4 + nf rows), attacking the ~600cyc L3-latency underfeed
//     (R6: VGPR=32, occupancy 47%, 2.67 TB/s on 409MB of L2-miss traffic)
//   - build CHUNK 4096->8192: halves partial-line write amplification in bins[]
// Fallback: exact 3-kernel CSR path if sizing fails.

#define F_DIM 16
#define BIN_SHIFT 6
#define BIN_NODES (1 << BIN_SHIFT)   // 64 receivers per bin
#define CHUNK 8192                   // edges per build block
#define STG (CHUNK / 256)            // staged edges per thread = 32
#define CAP_LDS 2816                 // max edges per bin in gather LDS (11.3 KB)

__global__ void __launch_bounds__(256) init_kernel(int* __restrict__ binCur,
                                                   int nbins, int cap)
{
    int b = blockIdx.x * blockDim.x + threadIdx.x;
    if (b < nbins) binCur[b] = b * cap;
}

__global__ void __launch_bounds__(256) pos_pack_kernel(
    const float* __restrict__ pos, float4* __restrict__ posf4, int N)
{
    int n = blockIdx.x * blockDim.x + threadIdx.x;
    if (n >= N) return;
    posf4[n] = make_float4(pos[3*n], pos[3*n+1], pos[3*n+2], 0.f);
}

__global__ void __launch_bounds__(256) build_bins_kernel(
    const int* __restrict__ senders, const int* __restrict__ receivers,
    int* __restrict__ binCur, int* __restrict__ bins,
    int nbins, int cap, int E)
{
    __shared__ int hist[2048];
    int t = threadIdx.x;
    for (int i = t; i < nbins; i += 256) hist[i] = 0;
    __syncthreads();

    int base = blockIdx.x * CHUNK;
    unsigned pk[STG], br[STG];
#pragma unroll
    for (int k = 0; k < STG; ++k) {
        int e = base + k * 256 + t;
        if (e < E) {
            int r = receivers[e];
            int s = senders[e];
            int bb = r >> BIN_SHIFT;
            int rank = atomicAdd(&hist[bb], 1);              // LDS atomic
            pk[k] = ((unsigned)s << BIN_SHIFT) | (unsigned)(r & (BIN_NODES - 1));
            br[k] = ((unsigned)bb << 13) | (unsigned)rank;   // bb<2048, rank<8192
        } else {
            br[k] = 0xFFFFFFFFu;                             // sentinel > any valid
        }
    }
    __syncthreads();

    // one global cursor atomic per (block, nonzero bin); stash gbase in hist[]
    for (int i = t; i < nbins; i += 256) {
        int c = hist[i];
        if (c > 0) hist[i] = atomicAdd(&binCur[i], c);
    }
    __syncthreads();

#pragma unroll
    for (int k = 0; k < STG; ++k) {
        if (br[k] == 0xFFFFFFFFu) continue;
        int bb   = (int)(br[k] >> 13);
        int rank = (int)(br[k] & 8191u);
        int dest = hist[bb] + rank;
        if (dest < (bb + 1) * cap)   // overflow clip (prob ~1e-13)
            bins[dest] = (int)pk[k];
    }
}

// one edge: receiver pos pr, sender pos sp, feature row fx -> accumulate
__device__ __forceinline__ void edge_acc(
    const float4& pr, const float4& sp, const float4& fx,
    float& a0, float& a1, float& a2, float& a3)
{
    const float INV_S3 = 0.5773502691896258f;
    const float INV_S2 = 0.7071067811865476f;
    float dx = pr.x - sp.x;
    float dy = pr.y - sp.y;
    float dz = pr.z - sp.z;
    float d2 = dx*dx + dy*dy + dz*dz;
    float inv = __builtin_amdgcn_rsqf(fmaxf(d2, 1e-18f));  // self-edge -> d=0
    dx *= inv; dy *= inv; dz *= inv;
    float dot = fx.y*dx + fx.z*dy + fx.w*dz;
    a0 += fx.x + dot * INV_S3;
    float c0 = fx.z*dz - fx.w*dy;
    float c1 = fx.w*dx - fx.y*dz;
    float c2 = fx.y*dy - fx.z*dx;
    a1 += fx.x*dx + fx.y + c0 * INV_S2;
    a2 += fx.x*dy + fx.z + c1 * INV_S2;
    a3 += fx.x*dz + fx.w + c2 * INV_S2;
}

__global__ void __launch_bounds__(256) bin_gather_kernel(
    const float4* __restrict__ posf4,
    const float* __restrict__ nf,
    const int* __restrict__ bins,
    const int* __restrict__ binCur,
    const float* __restrict__ W,
    const float* __restrict__ Bias,
    float* __restrict__ out,
    int N, int cap)
{
    __shared__ int lcsr[CAP_LDS];          // senders, grouped by local node
    __shared__ int lhist[BIN_NODES];       // hist, then scatter cursor
    __shared__ int lscan[BIN_NODES];       // inclusive scan (end offsets)
    __shared__ int lstart[BIN_NODES];      // exclusive scan (start offsets)

    int t = threadIdx.x;
    int bin = blockIdx.x;
    int node0 = bin << BIN_SHIFT;
    int gbase = bin * cap;

    int cnt = binCur[bin] - gbase;
    if (cnt > cap) cnt = cap;

    if (t < BIN_NODES) lhist[t] = 0;
    __syncthreads();

    // pass 1: histogram local receivers (1 int LDS atomic per edge)
    for (int j = t; j < cnt; j += 256)
        atomicAdd(&lhist[((unsigned)bins[gbase + j]) & (BIN_NODES - 1)], 1);
    __syncthreads();

    // 64-wide Hillis-Steele scan
    if (t < BIN_NODES) lscan[t] = lhist[t];
    __syncthreads();
    for (int off = 1; off < BIN_NODES; off <<= 1) {
        int v = (t < BIN_NODES && t >= off) ? lscan[t - off] : 0;
        __syncthreads();
        if (t < BIN_NODES) lscan[t] += v;
        __syncthreads();
    }
    if (t < BIN_NODES) { lstart[t] = lscan[t] - lhist[t]; lhist[t] = 0; }
    __syncthreads();

    // pass 2: scatter senders into local CSR (1 int LDS atomic per edge)
    for (int j = t; j < cnt; j += 256) {
        unsigned pk = (unsigned)bins[gbase + j];
        int rl = (int)(pk & (BIN_NODES - 1));
        int rank = atomicAdd(&lhist[rl], 1);
        lcsr[lstart[rl] + rank] = (int)(pk >> BIN_SHIFT);
    }
    __syncthreads();

    // register gather: thread (node, f); 4 nodes per thread; unroll x4 for MLP
    float w[16];
#pragma unroll
    for (int i = 0; i < 16; ++i) w[i] = W[i];
    float b0 = Bias[0], b1 = Bias[1], b2 = Bias[2], b3 = Bias[3];
    const float sc = 1.0f / 32.0f;

    int f = t & 15;
    const float4* nf4 = (const float4*)nf;

    for (int nl = t >> 4; nl < BIN_NODES; nl += 16) {
        int n = node0 + nl;
        if (n >= N) break;
        float4 pr = posf4[n];
        int s0 = lstart[nl];
        int dcnt = lscan[nl] - s0;

        float a0 = 0.f, a1 = 0.f, a2 = 0.f, a3 = 0.f;
        int j = 0;
        for (; j + 4 <= dcnt; j += 4) {
            int s_0 = lcsr[s0 + j + 0];
            int s_1 = lcsr[s0 + j + 1];
            int s_2 = lcsr[s0 + j + 2];
            int s_3 = lcsr[s0 + j + 3];
            // 8 independent global loads issued before any use
            float4 p0 = posf4[s_0];
            float4 p1 = posf4[s_1];
            float4 p2 = posf4[s_2];
            float4 p3 = posf4[s_3];
            float4 q0 = nf4[(unsigned)(s_0 * F_DIM + f)];
            float4 q1 = nf4[(unsigned)(s_1 * F_DIM + f)];
            float4 q2 = nf4[(unsigned)(s_2 * F_DIM + f)];
            float4 q3 = nf4[(unsigned)(s_3 * F_DIM + f)];
            edge_acc(pr, p0, q0, a0, a1, a2, a3);
            edge_acc(pr, p1, q1, a0, a1, a2, a3);
            edge_acc(pr, p2, q2, a0, a1, a2, a3);
            edge_acc(pr, p3, q3, a0, a1, a2, a3);
        }
        for (; j < dcnt; ++j) {
            int s = lcsr[s0 + j];
            float4 p = posf4[s];
            float4 q = nf4[(unsigned)(s * F_DIM + f)];
            edge_acc(pr, p, q, a0, a1, a2, a3);
        }

        a0 *= sc; a1 *= sc; a2 *= sc; a3 *= sc;
        float4 o;
        o.x = a0*w[0] + a1*w[4] + a2*w[8]  + a3*w[12] + b0;
        o.y = a0*w[1] + a1*w[5] + a2*w[9]  + a3*w[13] + b1;
        o.z = a0*w[2] + a1*w[6] + a2*w[10] + a3*w[14] + b2;
        o.w = a0*w[3] + a1*w[7] + a2*w[11] + a3*w[15] + b3;
        ((float4*)out)[(size_t)n * F_DIM + f] = o;      // coalesced
    }
}

// ---------------- fallback: exact CSR path (round 3) ----------------
__global__ void __launch_bounds__(256) hist_kernel(
    const int* __restrict__ receivers, int* __restrict__ deg,
    int* __restrict__ rank, int E)
{
    int e = blockIdx.x * blockDim.x + threadIdx.x;
    if (e >= E) return;
    rank[e] = atomicAdd(&deg[receivers[e]], 1);
}

__global__ void __launch_bounds__(256) alloc_kernel(
    const int* __restrict__ deg, int* __restrict__ start,
    int* __restrict__ cursor, int N)
{
    __shared__ int tmp[256];
    __shared__ int base;
    int t = threadIdx.x;
    int n = blockIdx.x * blockDim.x + t;
    int v = (n < N) ? deg[n] : 0;
    tmp[t] = v;
    __syncthreads();
    for (int off = 1; off < 256; off <<= 1) {
        int x = (t >= off) ? tmp[t - off] : 0;
        __syncthreads();
        tmp[t] += x;
        __syncthreads();
    }
    int incl = tmp[t];
    if (t == 255) base = atomicAdd(cursor, incl);
    __syncthreads();
    if (n < N) start[n] = base + incl - v;
}

__global__ void __launch_bounds__(256) scatter_kernel(
    const int* __restrict__ senders, const int* __restrict__ receivers,
    const int* __restrict__ rank, const int* __restrict__ start,
    int* __restrict__ csr_s, int E)
{
    int e = blockIdx.x * blockDim.x + threadIdx.x;
    if (e >= E) return;
    csr_s[start[receivers[e]] + rank[e]] = senders[e];
}

__global__ void __launch_bounds__(256) gather_kernel(
    const float* __restrict__ pos,
    const float* __restrict__ nf,
    const int* __restrict__ csr_s,
    const int* __restrict__ start,
    const int* __restrict__ deg,
    const float* __restrict__ W,
    const float* __restrict__ b,
    float* __restrict__ out,
    int N)
{
    const float INV_S3 = 0.5773502691896258f;
    const float INV_S2 = 0.7071067811865476f;

    int tid = blockIdx.x * blockDim.x + threadIdx.x;
    int n = tid >> 4;
    if (n >= N) return;
    int f = tid & 15;

    float rx = pos[3*n], ry = pos[3*n+1], rz = pos[3*n+2];
    int s0 = start[n];
    int dcnt = deg[n];
    float a0 = 0.f, a1 = 0.f, a2 = 0.f, a3 = 0.f;
    const float4* nf4 = (const float4*)nf;

    int s = (dcnt > 0) ? csr_s[s0] : 0;
    for (int j = 0; j < dcnt; ++j) {
        int s_next = (j + 1 < dcnt) ? csr_s[s0 + j + 1] : 0;
        float dx = rx - pos[3*s], dy = ry - pos[3*s+1], dz = rz - pos[3*s+2];
        float d2 = dx*dx + dy*dy + dz*dz;
        float inv = __builtin_amdgcn_rsqf(fmaxf(d2, 1e-18f));
        dx *= inv; dy *= inv; dz *= inv;
        float4 x = nf4[(unsigned)(s * F_DIM + f)];
        float x0 = x.x, x1 = x.y, x2 = x.z, x3 = x.w;
        float dot = x1*dx + x2*dy + x3*dz;
        a0 += x0 + dot * INV_S3;
        float c0 = x2*dz - x3*dy, c1 = x3*dx - x1*dz, c2 = x1*dy - x2*dx;
        a1 += x0*dx + x1 + c0 * INV_S2;
        a2 += x0*dy + x2 + c1 * INV_S2;
        a3 += x0*dz + x3 + c2 * INV_S2;
        s = s_next;
    }
    const float sc = 1.0f / 32.0f;
    a0 *= sc; a1 *= sc; a2 *= sc; a3 *= sc;
    float4 o;
    o.x = a0*W[0] + a1*W[4] + a2*W[8]  + a3*W[12] + b[0];
    o.y = a0*W[1] + a1*W[5] + a2*W[9]  + a3*W[13] + b[1];
    o.z = a0*W[2] + a1*W[6] + a2*W[10] + a3*W[14] + b[2];
    o.w = a0*W[3] + a1*W[7] + a2*W[11] + a3*W[15] + b[3];
    ((float4*)out)[tid] = o;
}

extern "C" void kernel_launch(void* const* d_in, const int* in_sizes, int n_in,
                              void* d_out, int out_size, void* d_ws, size_t ws_size,
                              hipStream_t stream)
{
    const float* pos       = (const float*)d_in[0];
    const float* nf        = (const float*)d_in[1];
    const float* W         = (const float*)d_in[2];
    const float* b         = (const float*)d_in[3];
    const int*   senders   = (const int*)d_in[4];
    const int*   receivers = (const int*)d_in[5];

    int N = in_sizes[0] / 3;
    int E = in_sizes[4];
    float* out = (float*)d_out;
    const int blk = 256;

    int nbins = (N + BIN_NODES - 1) >> BIN_SHIFT;
    int cap   = E / nbins + 453;   // mean + ~10 sigma (Poisson)
    size_t need = ((size_t)N * 4 + (size_t)nbins * cap + nbins) * sizeof(float);

    if (nbins <= 2048 && cap <= CAP_LDS && ws_size >= need) {
        // ws layout: [posf4(N float4)][binCur(nbins)][bins(nbins*cap)]
        float4* posf4 = (float4*)d_ws;
        int* binCur = (int*)(posf4 + N);
        int* bins   = binCur + nbins;

        pos_pack_kernel<<<(N + blk - 1) / blk, blk, 0, stream>>>(pos, posf4, N);
        init_kernel<<<(nbins + blk - 1) / blk, blk, 0, stream>>>(binCur, nbins, cap);
        build_bins_kernel<<<(E + CHUNK - 1) / CHUNK, blk, 0, stream>>>(
            senders, receivers, binCur, bins, nbins, cap, E);
        bin_gather_kernel<<<nbins, blk, 0, stream>>>(
            posf4, nf, bins, binCur, W, b, out, N, cap);
    } else {
        // ws layout: [cursor(1)][deg(N)][start(N)][rank(E)][csr_s(E)]
        int* cursor = (int*)d_ws;
        int* deg    = cursor + 1;
        int* start  = deg + N;
        int* rank   = start + N;
        int* csr_s  = rank + E;

        hipMemsetAsync(cursor, 0, (size_t)(1 + N) * sizeof(int), stream);
        hist_kernel<<<(E + blk - 1) / blk, blk, 0, stream>>>(receivers, deg, rank, E);
        alloc_kernel<<<(N + blk - 1) / blk, blk, 0, stream>>>(deg, start, cursor, N);
        scatter_kernel<<<(E + blk - 1) / blk, blk, 0, stream>>>(
            senders, receivers, rank, start, csr_s, E);
        long total = (long)N * F_DIM;
        gather_kernel<<<(unsigned)((total + blk - 1) / blk), blk, 0, stream>>>(
            pos, nf, csr_s, start, deg, W, b, out, N);
    }
}